// Round 3
// baseline (33.662 us; speedup 1.0000x reference)
//
#include <hip/hip_runtime.h>
#include <hip/hip_bf16.h>

typedef __attribute__((ext_vector_type(8))) short short8;
typedef __attribute__((ext_vector_type(4))) float f32x4;

#define C_COUPLING 1.0f
#define C_DT 1.0f
#define C_ATTR 1.0f
#define LDS_PITCH 136   // 128 + 8 pad shorts; rows stay 16B-aligned (272B)

// float -> bf16 bits (round-to-nearest-ish via +0x8000; inputs finite, |v|<=1)
__device__ __forceinline__ short f2bf(float f) {
  unsigned u = __builtin_bit_cast(unsigned, f);
  return (short)((u + 0x8000u) >> 16);
}

// out = theta + DT*ATTR*(gamma - theta); one float4 per thread.
__global__ __launch_bounds__(256) void vk_init(const float* __restrict__ th,
                                               const float* __restrict__ ga,
                                               float* __restrict__ out, int n4) {
  int i = blockIdx.x * blockDim.x + threadIdx.x;
  if (i < n4) {
    const float4 t = ((const float4*)th)[i];
    const float4 g = ((const float4*)ga)[i];
    float4 o;
    o.x = t.x + C_DT * (C_ATTR * (g.x - t.x));
    o.y = t.y + C_DT * (C_ATTR * (g.y - t.y));
    o.z = t.z + C_DT * (C_ATTR * (g.z - t.z));
    o.w = t.w + C_DT * (C_ATTR * (g.w - t.w));
    ((float4*)out)[i] = o;
  }
}

// Each wave owns one 16-row i-tile of batch b and a 128-wide j-chunk.
// P = (A.*cos(alpha)) x [sin|cos](theta)  (cols 0-7 s-part, 8-15 c-part)
// Q = (A.*sin(alpha)) x [sin|cos](theta)
// coupling(i,d) = (C/N) * ( c_i*(P[d] - Q[d+8]) - s_i*(P[d+8] + Q[d]) )
// B-operand trig table lives in LDS, computed per block (jChunk==128 assumed).
__global__ __launch_bounds__(256) void vk_main(
    const float* __restrict__ theta,
    const float* __restrict__ affinity,
    const float* __restrict__ alpha,
    float* __restrict__ out,
    int N, int jsCnt, int jChunk) {
  __shared__ unsigned short T[16 * LDS_PITCH];   // 4352 B

  const int jc = blockIdx.x % jsCnt;
  int t = blockIdx.x / jsCnt;
  const int nib = N >> 6;            // i-blocks of 64 rows
  const int ib = t % nib;
  const int b = t / nib;
  const int j0 = jc * jChunk;

  // ---- fill trig table: rows 0-7 = sin(theta[.,.,d]), 8-15 = cos ----
  {
    const int tid = threadIdx.x;
    const int half = tid >> 7;               // 0 -> sin, 1 -> cos
    for (int j = tid & 127; j < jChunk; j += 128) {
      const float* tp = theta + (((size_t)b * N + j0 + j) << 3);
      const float4 t0 = *(const float4*)tp;
      const float4 t1 = *(const float4*)(tp + 4);
      const float v[8] = {t0.x, t0.y, t0.z, t0.w, t1.x, t1.y, t1.z, t1.w};
      #pragma unroll
      for (int d = 0; d < 8; ++d) {
        const float val = half ? __cosf(v[d]) : __sinf(v[d]);
        T[(half * 8 + d) * LDS_PITCH + j] = (unsigned short)f2bf(val);
      }
    }
  }
  __syncthreads();

  const int wave = threadIdx.x >> 6;
  const int lane = threadIdx.x & 63;
  const int itile = ib * 4 + wave;   // 16-row tile
  const int g = lane >> 4;           // k-group 0..3
  const int col = lane & 15;         // A row (M) / B col (N) index
  const int arow = itile * 16 + col;

  const float* __restrict__ Arow = affinity + ((size_t)b * N + arow) * (size_t)N + j0;
  const float* __restrict__ Lrow = alpha    + ((size_t)b * N + arow) * (size_t)N + j0;
  const unsigned short* __restrict__ Trow = T + col * LDS_PITCH;

  f32x4 P = {0.f, 0.f, 0.f, 0.f};
  f32x4 Q = {0.f, 0.f, 0.f, 0.f};

  // depth-2 software pipeline over 32-j tiles; requires jChunk%64==0, >=64
  float4 xa0, xa1, xl0, xl1; short8 xbf;
  float4 ya0, ya1, yl0, yl1; short8 ybf;

  auto LOADX = [&](int jt) {
    const int o = jt + g * 8;
    xa0 = *(const float4*)(Arow + o);
    xa1 = *(const float4*)(Arow + o + 4);
    xl0 = *(const float4*)(Lrow + o);
    xl1 = *(const float4*)(Lrow + o + 4);
    xbf = *(const short8*)(Trow + o);
  };
  auto LOADY = [&](int jt) {
    const int o = jt + g * 8;
    ya0 = *(const float4*)(Arow + o);
    ya1 = *(const float4*)(Arow + o + 4);
    yl0 = *(const float4*)(Lrow + o);
    yl1 = *(const float4*)(Lrow + o + 4);
    ybf = *(const short8*)(Trow + o);
  };
  auto STEPX = [&]() {
    const float av[8] = {xa0.x, xa0.y, xa0.z, xa0.w, xa1.x, xa1.y, xa1.z, xa1.w};
    const float lv[8] = {xl0.x, xl0.y, xl0.z, xl0.w, xl1.x, xl1.y, xl1.z, xl1.w};
    short8 wc, ws;
    #pragma unroll
    for (int k = 0; k < 8; ++k) {
      const float sv = __sinf(lv[k]);
      const float cv = __cosf(lv[k]);
      wc[k] = f2bf(av[k] * cv);
      ws[k] = f2bf(av[k] * sv);
    }
    P = __builtin_amdgcn_mfma_f32_16x16x32_bf16(wc, xbf, P, 0, 0, 0);
    Q = __builtin_amdgcn_mfma_f32_16x16x32_bf16(ws, xbf, Q, 0, 0, 0);
  };
  auto STEPY = [&]() {
    const float av[8] = {ya0.x, ya0.y, ya0.z, ya0.w, ya1.x, ya1.y, ya1.z, ya1.w};
    const float lv[8] = {yl0.x, yl0.y, yl0.z, yl0.w, yl1.x, yl1.y, yl1.z, yl1.w};
    short8 wc, ws;
    #pragma unroll
    for (int k = 0; k < 8; ++k) {
      const float sv = __sinf(lv[k]);
      const float cv = __cosf(lv[k]);
      wc[k] = f2bf(av[k] * cv);
      ws[k] = f2bf(av[k] * sv);
    }
    P = __builtin_amdgcn_mfma_f32_16x16x32_bf16(wc, ybf, P, 0, 0, 0);
    Q = __builtin_amdgcn_mfma_f32_16x16x32_bf16(ws, ybf, Q, 0, 0, 0);
  };

  LOADX(0);
  LOADY(32);
  int jt = 0;
  while (jt + 64 < jChunk) {
    STEPX(); LOADX(jt + 64);
    STEPY(); LOADY(jt + 96);
    jt += 64;
  }
  STEPX();
  STEPY();

  // C/D layout: col = lane&15, row = (lane>>4)*4 + reg  [m89]
  // lane col=d needs cols d+8 -> partner lane = lane ^ 8 (same g, same rows)
  float pc[4], qc[4];
  #pragma unroll
  for (int r = 0; r < 4; ++r) {
    pc[r] = __shfl_xor(P[r], 8, 64);
    qc[r] = __shfl_xor(Q[r], 8, 64);
  }
  if (col < 8) {
    const float sc = C_COUPLING / (float)N;
    #pragma unroll
    for (int r = 0; r < 4; ++r) {
      const int i = itile * 16 + g * 4 + r;
      const size_t oi = (((size_t)b * N + i) << 3) + col;
      const float thi = theta[oi];
      const float sv = __sinf(thi);
      const float cv = __cosf(thi);
      const float coup = sc * (cv * (P[r] - qc[r]) - sv * (pc[r] + Q[r]));
      unsafeAtomicAdd(out + oi, coup);
    }
  }
}

extern "C" void kernel_launch(void* const* d_in, const int* in_sizes, int n_in,
                              void* d_out, int out_size, void* d_ws, size_t ws_size,
                              hipStream_t stream) {
  const float* theta = (const float*)d_in[0];
  const float* gamma = (const float*)d_in[1];
  const float* aff   = (const float*)d_in[2];
  const float* alp   = (const float*)d_in[3];
  float* out = (float*)d_out;

  const long t0 = in_sizes[0];              // B*N*D (D=8)
  const long t2 = in_sizes[2];              // B*N*N
  const int N = (int)(8 * t2 / t0);
  const int B = (int)(t0 / ((long)N * 8));

  const int n4 = B * N * 2;                 // float4 count
  vk_init<<<dim3((n4 + 255) / 256), dim3(256), 0, stream>>>(theta, gamma, out, n4);

  // jChunk fixed at 128 (LDS table width); requires N % 128 == 0
  const int jChunk = 128;
  const int js = N / jChunk;
  dim3 grid(B * (N / 64) * js);
  vk_main<<<grid, dim3(256), 0, stream>>>(theta, aff, alp, out, N, js, jChunk);
}

// Round 4
// 33.149 us; speedup vs baseline: 1.0155x; 1.0155x over previous
//
#include <hip/hip_runtime.h>
#include <hip/hip_bf16.h>

typedef __attribute__((ext_vector_type(8))) short short8;
typedef __attribute__((ext_vector_type(4))) float f32x4;

#define C_COUPLING 1.0f
#define C_DT 1.0f
#define C_ATTR 1.0f

#define JCH 128          // j-chunk per block
#define TILE_J 32        // j per pipeline step
#define NT (JCH / TILE_J)
#define TPITCH 136       // trig-table pitch in shorts (272B = 17*16B, odd quads)

// T: 16 rows x TPITCH shorts = 4352B; A/L staging: 4 waves x 2 buf x (A 2KB + L 2KB)
#define LDS_T_BYTES (16 * TPITCH * 2)
#define LDS_WAVE_BYTES (2 * 4096)
#define LDS_TOTAL (LDS_T_BYTES + 4 * LDS_WAVE_BYTES)

typedef __attribute__((address_space(3))) unsigned lds_u32;
typedef __attribute__((address_space(1))) const unsigned g_u32;

__device__ __forceinline__ void gl_lds16(const float* g, void* l) {
  // 16B per lane: global per-lane src -> LDS wave-uniform base + lane*16
  __builtin_amdgcn_global_load_lds((g_u32*)g, (lds_u32*)l, 16, 0, 0);
}

#define WAITVM(n) do { asm volatile("s_waitcnt vmcnt(" #n ")" ::: "memory"); \
                       __builtin_amdgcn_sched_barrier(0); } while (0)

// float -> bf16 bits (round-to-nearest-ish; inputs finite, |v|<=1)
__device__ __forceinline__ short f2bf(float f) {
  unsigned u = __builtin_bit_cast(unsigned, f);
  return (short)((u + 0x8000u) >> 16);
}

// out = theta + DT*ATTR*(gamma - theta); one float4 per thread.
__global__ __launch_bounds__(256) void vk_init(const float* __restrict__ th,
                                               const float* __restrict__ ga,
                                               float* __restrict__ out, int n4) {
  int i = blockIdx.x * blockDim.x + threadIdx.x;
  if (i < n4) {
    const float4 t = ((const float4*)th)[i];
    const float4 g = ((const float4*)ga)[i];
    float4 o;
    o.x = t.x + C_DT * (C_ATTR * (g.x - t.x));
    o.y = t.y + C_DT * (C_ATTR * (g.y - t.y));
    o.z = t.z + C_DT * (C_ATTR * (g.z - t.z));
    o.w = t.w + C_DT * (C_ATTR * (g.w - t.w));
    ((float4*)out)[i] = o;
  }
}

// P = (A.*cos(alpha)) x [sin|cos](theta), Q = (A.*sin(alpha)) x [sin|cos](theta)
// coupling(i,d) = (C/N)*( c_i*(P[d]-Q[d+8]) - s_i*(P[d+8]+Q[d]) )
__global__ __launch_bounds__(256) void vk_main(
    const float* __restrict__ theta,
    const float* __restrict__ affinity,
    const float* __restrict__ alpha,
    float* __restrict__ out,
    int N, int jsCnt) {
  __shared__ __align__(16) unsigned char lds_raw[LDS_TOTAL];
  unsigned short* T = (unsigned short*)lds_raw;

  const int jc = blockIdx.x % jsCnt;
  int t = blockIdx.x / jsCnt;
  const int nib = N >> 6;
  const int ib = t % nib;
  const int b = t / nib;
  const int j0 = jc * JCH;

  // ---- trig table: rows 0-7 sin(theta[.,j,d]), rows 8-15 cos ----
  {
    const int tid = threadIdx.x;
    const int half = tid >> 7;           // 0 sin, 1 cos
    const int j = tid & 127;             // JCH == 128
    const float* tp = theta + (((size_t)b * N + j0 + j) << 3);
    const float4 t0 = *(const float4*)tp;
    const float4 t1 = *(const float4*)(tp + 4);
    const float v[8] = {t0.x, t0.y, t0.z, t0.w, t1.x, t1.y, t1.z, t1.w};
    #pragma unroll
    for (int d = 0; d < 8; ++d) {
      const float val = half ? __cosf(v[d]) : __sinf(v[d]);
      T[(half * 8 + d) * TPITCH + j] = (unsigned short)f2bf(val);
    }
  }
  __syncthreads();

  const int wave = threadIdx.x >> 6;
  const int lane = threadIdx.x & 63;
  const int itile = ib * 4 + wave;
  const int g = lane >> 4;
  const int col = lane & 15;

  unsigned char* wbase = lds_raw + LDS_T_BYTES + wave * LDS_WAVE_BYTES;

  // staging source addresses (per lane, swizzled: chunk c holds global chunk
  // c ^ (row&1) -> read-side spreads the 8 bank-quads evenly)
  const int srow = lane >> 3;                 // 0..7 within an 8-row group
  const int schk = (lane & 7) ^ (srow & 1);   // swizzled 16B chunk
  const size_t rowstep = (size_t)N;
  const size_t off0 = ((size_t)b * N + itile * 16 + srow) * rowstep + j0 + 4 * schk;
  const size_t off1 = off0 + 8 * rowstep;
  const float* pA0 = affinity + off0;
  const float* pA1 = affinity + off1;
  const float* pL0 = alpha + off0;
  const float* pL1 = alpha + off1;

  f32x4 P = {0.f, 0.f, 0.f, 0.f};
  f32x4 Q = {0.f, 0.f, 0.f, 0.f};

  const unsigned short* Trow = T + col * TPITCH;
  const int c0 = (2 * g) ^ (col & 1);       // chunk holding j = g*8..+3
  const int c1 = (2 * g + 1) ^ (col & 1);   // chunk holding j = g*8+4..+7

#define STAGE(buf, jt) do { \
    unsigned char* d_ = wbase + (buf) * 4096; \
    gl_lds16(pA0 + (jt), d_); \
    gl_lds16(pA1 + (jt), d_ + 1024); \
    gl_lds16(pL0 + (jt), d_ + 2048); \
    gl_lds16(pL1 + (jt), d_ + 3072); \
  } while (0)

#define COMPUTE(buf, jt) do { \
    const float* Ab = (const float*)(wbase + (buf) * 4096); \
    const float* Lb = Ab + 512; \
    const float4 a_lo = *(const float4*)(Ab + col * 32 + c0 * 4); \
    const float4 a_hi = *(const float4*)(Ab + col * 32 + c1 * 4); \
    const float4 l_lo = *(const float4*)(Lb + col * 32 + c0 * 4); \
    const float4 l_hi = *(const float4*)(Lb + col * 32 + c1 * 4); \
    const short8 bf = *(const short8*)(Trow + (jt) + g * 8); \
    const float av[8] = {a_lo.x, a_lo.y, a_lo.z, a_lo.w, a_hi.x, a_hi.y, a_hi.z, a_hi.w}; \
    const float lv[8] = {l_lo.x, l_lo.y, l_lo.z, l_lo.w, l_hi.x, l_hi.y, l_hi.z, l_hi.w}; \
    short8 wc, ws; \
    _Pragma("unroll") \
    for (int k = 0; k < 8; ++k) { \
      const float sv = __sinf(lv[k]); \
      const float cv = __cosf(lv[k]); \
      wc[k] = f2bf(av[k] * cv); \
      ws[k] = f2bf(av[k] * sv); \
    } \
    P = __builtin_amdgcn_mfma_f32_16x16x32_bf16(wc, bf, P, 0, 0, 0); \
    Q = __builtin_amdgcn_mfma_f32_16x16x32_bf16(ws, bf, Q, 0, 0, 0); \
  } while (0)

  // depth-1-ahead double-buffered pipeline, counted vmcnt (never 0 mid-loop)
  STAGE(0, 0);
  STAGE(1, TILE_J);
  WAITVM(4);            // tile 0 landed; tile 1 in flight
  COMPUTE(0, 0);
  STAGE(0, 2 * TILE_J);
  WAITVM(4);
  COMPUTE(1, TILE_J);
  STAGE(1, 3 * TILE_J);
  WAITVM(4);
  COMPUTE(0, 2 * TILE_J);
  WAITVM(0);
  COMPUTE(1, 3 * TILE_J);

#undef STAGE
#undef COMPUTE

  // C/D layout: col = lane&15, row = (lane>>4)*4 + reg  [m89]
  float pc[4], qc[4];
  #pragma unroll
  for (int r = 0; r < 4; ++r) {
    pc[r] = __shfl_xor(P[r], 8, 64);
    qc[r] = __shfl_xor(Q[r], 8, 64);
  }
  if (col < 8) {
    const float sc = C_COUPLING / (float)N;
    #pragma unroll
    for (int r = 0; r < 4; ++r) {
      const int i = itile * 16 + g * 4 + r;
      const size_t oi = (((size_t)b * N + i) << 3) + col;
      const float thi = theta[oi];
      const float sv = __sinf(thi);
      const float cv = __cosf(thi);
      const float coup = sc * (cv * (P[r] - qc[r]) - sv * (pc[r] + Q[r]));
      unsafeAtomicAdd(out + oi, coup);
    }
  }
}

extern "C" void kernel_launch(void* const* d_in, const int* in_sizes, int n_in,
                              void* d_out, int out_size, void* d_ws, size_t ws_size,
                              hipStream_t stream) {
  const float* theta = (const float*)d_in[0];
  const float* gamma = (const float*)d_in[1];
  const float* aff   = (const float*)d_in[2];
  const float* alp   = (const float*)d_in[3];
  float* out = (float*)d_out;

  const long t0 = in_sizes[0];              // B*N*D (D=8)
  const long t2 = in_sizes[2];              // B*N*N
  const int N = (int)(8 * t2 / t0);
  const int B = (int)(t0 / ((long)N * 8));

  const int n4 = B * N * 2;
  vk_init<<<dim3((n4 + 255) / 256), dim3(256), 0, stream>>>(theta, gamma, out, n4);

  const int js = N / JCH;                   // 16 for N=2048
  dim3 grid(B * (N / 64) * js);             // 2048 blocks
  vk_main<<<grid, dim3(256), 0, stream>>>(theta, aff, alp, out, N, js);
}